// Round 2
// baseline (508.047 us; speedup 1.0000x reference)
//
#include <hip/hip_runtime.h>

#define N_AB  1024
#define NHALF 1025
#define NFULL 2049
#define HDIM  64
#define PLANE ((size_t)N_AB * NFULL)

__device__ __forceinline__ float fast_tanh(float x) {
    // tanh(x) = (e^{2x}-1)/(e^{2x}+1); clamp so exp never overflows.
    x = fminf(fmaxf(x, -9.0f), 9.0f);
    float e = __builtin_amdgcn_exp2f(x * 2.885390081777927f); // exp(2x) = 2^(2x*log2e)
    return (e - 1.0f) * __builtin_amdgcn_rcpf(e + 1.0f);
}

// Evaluate one MLP (network n, abscissa x) + its JVP, produce xp,yp,xpp,ypp.
__device__ __forceinline__ float4 mlp_point(
    float x,
    const float* __restrict__ w0n, const float* __restrict__ b0n,
    const float* __restrict__ w1n, const float* __restrict__ b1n,
    const float* __restrict__ w2n, const float* __restrict__ b2n)
{
    float h[HDIM], dh[HDIM];
    #pragma unroll
    for (int j = 0; j < HDIM; ++j) {
        float w  = w0n[j];                    // block-uniform -> s_load
        float hj = fast_tanh(fmaf(w, x, b0n[j]));
        h[j]  = hj;
        dh[j] = (1.0f - hj * hj) * w;         // tangent of layer 1 (dx = 1)
    }
    float z30 = b2n[0], z31 = b2n[1];
    float dz30 = 0.0f, dz31 = 0.0f;
    #pragma unroll 2
    for (int i = 0; i < HDIM; ++i) {
        float acc = b1n[i], dacc = 0.0f;
        const float* __restrict__ row = w1n + i * HDIM;
        #pragma unroll
        for (int j = 0; j < HDIM; ++j) {
            float w = row[j];                 // block-uniform -> s_load (SGPR operand)
            acc  = fmaf(w, h[j],  acc);
            dacc = fmaf(w, dh[j], dacc);
        }
        float h2  = fast_tanh(acc);
        float dh2 = (1.0f - h2 * h2) * dacc;
        float w20 = w2n[i], w21 = w2n[HDIM + i];
        z30  = fmaf(w20, h2,  z30);
        dz30 = fmaf(w20, dh2, dz30);
        z31  = fmaf(w21, h2,  z31);
        dz31 = fmaf(w21, dh2, dz31);
    }
    float a  = z30 * z30;
    float bb = z31 * z31;
    float da = 2.0f * z30 * dz30;
    float db = 2.0f * z31 * dz31;
    float sa = __sinf(x), ca = __cosf(x);     // HW v_sin/v_cos; x in [0, pi]
    float cam1 = ca - 1.0f;
    float4 r;
    r.x = a * cam1;                    // xp
    r.y = bb * sa;                     // yp
    r.z = fmaf(da, cam1, -(a * sa));   // xpp
    r.w = fmaf(bb, ca, db * sa);       // ypp
    return r;
}

__global__ void __launch_bounds__(256)
__attribute__((amdgpu_waves_per_eu(2, 2)))   // pin occupancy target: 256-VGPR budget, stop scratch demotion
sofa_kernel(
    const float* __restrict__ alpha,
    const float* __restrict__ w0,
    const float* __restrict__ w1,
    const float* __restrict__ w2,
    const float* __restrict__ b0,
    const float* __restrict__ b1,
    const float* __restrict__ b2,
    float* __restrict__ out)
{
    const int n   = blockIdx.x;
    const int tid = threadIdx.x;

    const float* __restrict__ w0n = w0 + (size_t)n * HDIM;
    const float* __restrict__ b0n = b0 + (size_t)n * HDIM;
    const float* __restrict__ w1n = w1 + (size_t)n * HDIM * HDIM;
    const float* __restrict__ b1n = b1 + (size_t)n * HDIM;
    const float* __restrict__ w2n = w2 + (size_t)n * 2 * HDIM;
    const float* __restrict__ b2n = b2 + (size_t)n * 2;

    float* __restrict__ oxp  = out + (size_t)n * NFULL;
    float* __restrict__ oyp  = oxp + PLANE;
    float* __restrict__ oxpp = oxp + 2 * PLANE;
    float* __restrict__ oypp = oxp + 3 * PLANE;

    __shared__ float s_xplast;

    float rxp[4];

    // b = tid + 256k covers 0..1023 exactly (4*256 = 1024).
    #pragma unroll
    for (int k = 0; k < 4; ++k) {
        int b = tid + k * 256;
        float4 r = mlp_point(alpha[b], w0n, b0n, w1n, b1n, w2n, b2n);
        oxp[b]  = r.x;
        oyp[b]  = r.y;
        oxpp[b] = r.z;
        oypp[b] = r.w;
        int m = 2048 - b;            // mirror index, 1025..2048
        oyp[m]  = r.y;               // yp mirror:  +flip
        oxpp[m] = r.z;               // xpp mirror: +flip
        oypp[m] = -r.w;              // ypp mirror: -flip
        rxp[k] = r.x;
    }

    // b = 1024 (single odd point): one lane computes it; xp_last shared via LDS.
    if (tid == 0) {
        float4 r = mlp_point(alpha[NHALF - 1], w0n, b0n, w1n, b1n, w2n, b2n);
        oxp[NHALF - 1]  = r.x;
        oyp[NHALF - 1]  = r.y;
        oxpp[NHALF - 1] = r.z;
        oypp[NHALF - 1] = r.w;
        s_xplast = r.x;
    }
    __syncthreads();

    // xp mirror: xp[2048-b] = 2*xp_last - xp[b]
    float xl2 = 2.0f * s_xplast;
    #pragma unroll
    for (int k = 0; k < 4; ++k) {
        int b = tid + k * 256;
        oxp[2048 - b] = xl2 - rxp[k];
    }
}

extern "C" void kernel_launch(void* const* d_in, const int* in_sizes, int n_in,
                              void* d_out, int out_size, void* d_ws, size_t ws_size,
                              hipStream_t stream) {
    const float* alpha = (const float*)d_in[0];
    const float* w0    = (const float*)d_in[1];
    const float* w1    = (const float*)d_in[2];
    const float* w2    = (const float*)d_in[3];
    const float* b0    = (const float*)d_in[4];
    const float* b1    = (const float*)d_in[5];
    const float* b2    = (const float*)d_in[6];
    float* out = (float*)d_out;
    sofa_kernel<<<dim3(N_AB), dim3(256), 0, stream>>>(alpha, w0, w1, w2, b0, b1, b2, out);
}

// Round 3
// 66.298 us; speedup vs baseline: 7.6630x; 7.6630x over previous
//
#include <hip/hip_runtime.h>

#define N_AB  1024
#define NHALF 1025
#define NFULL 2049
#define HDIM  64
#define PLANE ((size_t)N_AB * NFULL)
#define C2L   2.8853900817779268f   // 2*log2(e)

typedef __bf16 bf16x8 __attribute__((ext_vector_type(8)));
typedef float  f32x4  __attribute__((ext_vector_type(4)));

#define MFMA16(A,B,C) __builtin_amdgcn_mfma_f32_16x16x32_bf16(A,B,C,0,0,0)

// S = z * 2*log2e ; H = tanh(z) ; T = u - u^2 with u = 1/(1+2^S) ; note 1-H^2 = 4T.
// Graceful at +/-inf: exp2->inf => u=0 => H=1 ; exp2->0 => u=1 => H=-1. No clamp needed.
#define ACT1(S,H,T) { float _e = __builtin_amdgcn_exp2f(S); \
                      float _u = __builtin_amdgcn_rcpf(1.0f + _e); \
                      H = fmaf(-2.0f,_u,1.0f); T = fmaf(-_u,_u,_u); }

// one layer-1 element: WC = w0*C2L, BC = b0*C2L, W4 = 4*w0 ; packs h->BV[IDX], dh->BT[IDX]
#define L1E(IDX, WC, BC, W4, BV, BT) { float _s = fmaf(WC, x, BC); float _h,_t; \
                      ACT1(_s,_h,_t) \
                      BV[IDX] = (__bf16)_h; BT[IDX] = (__bf16)(_t * (W4)); }

#define L1OCT(WA,WB,BA,BB,V4A,V4B,BV,BT) \
    L1E(0, WA.x, BA.x, V4A.x, BV, BT) \
    L1E(1, WA.y, BA.y, V4A.y, BV, BT) \
    L1E(2, WA.z, BA.z, V4A.z, BV, BT) \
    L1E(3, WA.w, BA.w, V4A.w, BV, BT) \
    L1E(4, WB.x, BB.x, V4B.x, BV, BT) \
    L1E(5, WB.y, BB.y, V4B.y, BV, BT) \
    L1E(6, WB.z, BB.z, V4B.z, BV, BT) \
    L1E(7, WB.w, BB.w, V4B.w, BV, BT)

// one layer-2 element: ACC=z2pre, DACC=dz2pre, B1C=b1*C2L ; accumulates layer-3 partials
#define L2E(ACC,DACC,B1C,W20,W21) { \
    float _s = fmaf(ACC, C2L, B1C); float _h,_t; ACT1(_s,_h,_t) \
    float _dh = (_t*4.0f)*(DACC); \
    pv0 = fmaf(W20,_h,pv0); pv1 = fmaf(W21,_h,pv1); \
    pt0 = fmaf(W20,_dh,pt0); pt1 = fmaf(W21,_dh,pt1); }

#define L2RT(AV,AT,B1,WR0,WR1) \
    L2E(AV[0],AT[0],B1.x,WR0.x,WR1.x) \
    L2E(AV[1],AT[1],B1.y,WR0.y,WR1.y) \
    L2E(AV[2],AT[2],B1.z,WR0.z,WR1.z) \
    L2E(AV[3],AT[3],B1.w,WR0.w,WR1.w)

#define SC4(V,S) { V.x*=(S); V.y*=(S); V.z*=(S); V.w*=(S); }

// full per-point-tile pipeline; leaves xp,yp,xpp,ypp (+x) in scope
#define COMPUTE_TILE(X) \
    const float x = (X); \
    bf16x8 bv0, bv1, bt0, bt1; \
    L1OCT(w0A,w0B,b0A,b0B,w4A,w4B,bv0,bt0) \
    L1OCT(w0C,w0D,b0C,b0D,w4C,w4D,bv1,bt1) \
    const f32x4 zz = {0.0f,0.0f,0.0f,0.0f}; \
    f32x4 av0 = MFMA16(A01,bv1,MFMA16(A00,bv0,zz)); \
    f32x4 av1 = MFMA16(A11,bv1,MFMA16(A10,bv0,zz)); \
    f32x4 av2 = MFMA16(A21,bv1,MFMA16(A20,bv0,zz)); \
    f32x4 av3 = MFMA16(A31,bv1,MFMA16(A30,bv0,zz)); \
    f32x4 at0 = MFMA16(A01,bt1,MFMA16(A00,bt0,zz)); \
    f32x4 at1 = MFMA16(A11,bt1,MFMA16(A10,bt0,zz)); \
    f32x4 at2 = MFMA16(A21,bt1,MFMA16(A20,bt0,zz)); \
    f32x4 at3 = MFMA16(A31,bt1,MFMA16(A30,bt0,zz)); \
    float pv0=0.0f,pv1=0.0f,pt0=0.0f,pt1=0.0f; \
    L2RT(av0,at0,b1c0,w2a0,w2b0) \
    L2RT(av1,at1,b1c1,w2a1,w2b1) \
    L2RT(av2,at2,b1c2,w2a2,w2b2) \
    L2RT(av3,at3,b1c3,w2a3,w2b3) \
    pv0 += __shfl_xor(pv0,16); pv0 += __shfl_xor(pv0,32); \
    pv1 += __shfl_xor(pv1,16); pv1 += __shfl_xor(pv1,32); \
    pt0 += __shfl_xor(pt0,16); pt0 += __shfl_xor(pt0,32); \
    pt1 += __shfl_xor(pt1,16); pt1 += __shfl_xor(pt1,32); \
    const float z0 = pv0 + b20, z1 = pv1 + b21; \
    const float aa = z0*z0, bb = z1*z1; \
    const float da = 2.0f*z0*pt0, db = 2.0f*z1*pt1; \
    const float sa = __sinf(x), ca = __cosf(x); \
    const float cam1 = ca - 1.0f; \
    const float xp = aa*cam1, yp = bb*sa; \
    const float xpp = fmaf(da,cam1,-(aa*sa)); \
    const float ypp = fmaf(bb,ca, db*sa);

__global__ void __launch_bounds__(256, 2) sofa_kernel(
    const float* __restrict__ alpha,
    const float* __restrict__ w0,
    const float* __restrict__ w1,
    const float* __restrict__ w2,
    const float* __restrict__ b0,
    const float* __restrict__ b1,
    const float* __restrict__ b2,
    float* __restrict__ out)
{
    __shared__ __align__(16) __bf16 w1s[HDIM * HDIM];   // XOR-swizzled bf16 W1
    __shared__ float s_alpha[NHALF];
    __shared__ float s_xplast;

    const int n    = blockIdx.x;
    const int tid  = threadIdx.x;
    const int lane = tid & 63;
    const int wid  = tid >> 6;
    const int col  = lane & 15;   // MFMA col (point) / A-row index
    const int grp  = lane >> 4;   // k-slot group / output-plane selector

    const float* __restrict__ w0n = w0 + (size_t)n * HDIM;
    const float* __restrict__ b0n = b0 + (size_t)n * HDIM;
    const float* __restrict__ w1n = w1 + (size_t)n * HDIM * HDIM;
    const float* __restrict__ b1n = b1 + (size_t)n * HDIM;
    const float* __restrict__ w2n = w2 + (size_t)n * 2 * HDIM;
    const float* __restrict__ b2n = b2 + (size_t)n * 2;

    // ---- stage alpha (fp32) and W1 (bf16, 16B-group XOR swizzle) into LDS ----
    for (int e = tid; e < NHALF; e += 256) s_alpha[e] = alpha[e];
    for (int e = tid; e < HDIM * HDIM; e += 256) {
        int i = e >> 6, j = e & 63;
        w1s[i * 64 + ((((j >> 3) ^ (i & 7))) << 3) + (j & 7)] = (__bf16)w1n[e];
    }
    __syncthreads();

    // ---- per-lane hoisted constants (all named scalars / float4 -> SSA, no allocas) ----
    const int jb0 = grp * 8, jb1 = 32 + grp * 8;
    float4 w0A = *(const float4*)(w0n + jb0);
    float4 w0B = *(const float4*)(w0n + jb0 + 4);
    float4 w0C = *(const float4*)(w0n + jb1);
    float4 w0D = *(const float4*)(w0n + jb1 + 4);
    float4 w4A = w0A, w4B = w0B, w4C = w0C, w4D = w0D;
    SC4(w4A, 4.0f) SC4(w4B, 4.0f) SC4(w4C, 4.0f) SC4(w4D, 4.0f)
    SC4(w0A, C2L)  SC4(w0B, C2L)  SC4(w0C, C2L)  SC4(w0D, C2L)
    float4 b0A = *(const float4*)(b0n + jb0);
    float4 b0B = *(const float4*)(b0n + jb0 + 4);
    float4 b0C = *(const float4*)(b0n + jb1);
    float4 b0D = *(const float4*)(b0n + jb1 + 4);
    SC4(b0A, C2L) SC4(b0B, C2L) SC4(b0C, C2L) SC4(b0D, C2L)

    float4 b1c0 = *(const float4*)(b1n + 0  + grp * 4);
    float4 b1c1 = *(const float4*)(b1n + 16 + grp * 4);
    float4 b1c2 = *(const float4*)(b1n + 32 + grp * 4);
    float4 b1c3 = *(const float4*)(b1n + 48 + grp * 4);
    SC4(b1c0, C2L) SC4(b1c1, C2L) SC4(b1c2, C2L) SC4(b1c3, C2L)

    const float4 w2a0 = *(const float4*)(w2n + 0  + grp * 4);
    const float4 w2a1 = *(const float4*)(w2n + 16 + grp * 4);
    const float4 w2a2 = *(const float4*)(w2n + 32 + grp * 4);
    const float4 w2a3 = *(const float4*)(w2n + 48 + grp * 4);
    const float4 w2b0 = *(const float4*)(w2n + 64 + 0  + grp * 4);
    const float4 w2b1 = *(const float4*)(w2n + 64 + 16 + grp * 4);
    const float4 w2b2 = *(const float4*)(w2n + 64 + 32 + grp * 4);
    const float4 w2b3 = *(const float4*)(w2n + 64 + 48 + grp * 4);
    const float b20 = b2n[0], b21 = b2n[1];

    // ---- A-fragments: W1 rows in registers (lane: row=col, k = 32*KH + 8*grp + 0..7) ----
    const bf16x8* w1v = (const bf16x8*)w1s;
    const int sw = col & 7;
#define AF(RT,KH) w1v[((RT)*16 + col)*8 + (((KH)*4 + grp) ^ sw)]
    const bf16x8 A00 = AF(0,0), A01 = AF(0,1), A10 = AF(1,0), A11 = AF(1,1);
    const bf16x8 A20 = AF(2,0), A21 = AF(2,1), A30 = AF(3,0), A31 = AF(3,1);

    const size_t obase = (size_t)grp * PLANE + (size_t)n * NFULL;

    // ---- point 1024 first (wave 0), to get xp_last for the xp mirror ----
    if (wid == 0) {
        COMPUTE_TILE(s_alpha[1024])
        if (col == 0) {
            out[obase + 1024] = (grp == 0) ? xp : (grp == 1) ? yp : (grp == 2) ? xpp : ypp;
            if (grp == 0) s_xplast = xp;
        }
    }
    __syncthreads();
    const float xl2 = 2.0f * s_xplast;

    // ---- main loop: 16 iters/wave, 16 points each; covers b = 0..1023 ----
    #pragma unroll 1
    for (int it = 0; it < 16; ++it) {
        const int p = ((it * 4 + wid) << 4) + col;
        COMPUTE_TILE(s_alpha[p])
        const float vdir = (grp == 0) ? xp : (grp == 1) ? yp : (grp == 2) ? xpp : ypp;
        const float vmir = (grp == 0) ? (xl2 - xp)
                         : (grp == 1) ? yp
                         : (grp == 2) ? xpp : -ypp;
        out[obase + p] = vdir;
        out[obase + (2048 - p)] = vmir;
    }
}

extern "C" void kernel_launch(void* const* d_in, const int* in_sizes, int n_in,
                              void* d_out, int out_size, void* d_ws, size_t ws_size,
                              hipStream_t stream) {
    const float* alpha = (const float*)d_in[0];
    const float* w0    = (const float*)d_in[1];
    const float* w1    = (const float*)d_in[2];
    const float* w2    = (const float*)d_in[3];
    const float* b0    = (const float*)d_in[4];
    const float* b1    = (const float*)d_in[5];
    const float* b2    = (const float*)d_in[6];
    float* out = (float*)d_out;
    sofa_kernel<<<dim3(N_AB), dim3(256), 0, stream>>>(alpha, w0, w1, w2, b0, b1, b2, out);
}